// Round 13
// baseline (315.865 us; speedup 1.0000x reference)
//
#include <hip/hip_runtime.h>
#include <hip/hip_bf16.h>

#define NN 8192
#define EE 262144
#define HID 64

typedef _Float16 half4_t __attribute__((ext_vector_type(4)));
typedef _Float16 half8_t __attribute__((ext_vector_type(8)));
typedef float f32x4 __attribute__((ext_vector_type(4)));

extern "C" __device__ float __ocml_native_exp2_f32(float);
#define EXP2N(x) __ocml_native_exp2_f32(x)

#define MFMA16(a, b, c) __builtin_amdgcn_mfma_f32_16x16x16f16(a, b, c, 0, 0, 0)

// ---------------------------------------------------------------- MFMA GEMM body
// (f16 inputs staged in LDS, f32 acc). Fragment conventions as verified:
//   mfma(X,Y,C): D layout col=lane&15, row=4*(lane>>4)+reg; frag lane: [lane&15][4g+i]
// BN=true: A-staging applies y = relu(a*bnsc[c]+bnsh[c])  (c = K-dim index, K==64)
template<bool TRANS_B, bool OUT_F16, int ACT, bool GAT, bool BN>
__device__ __forceinline__ void mfma_gemm_body(
        const float* __restrict__ A, const float* __restrict__ B,
        const float* __restrict__ bias, void* __restrict__ Cout,
        int M, int Nc, int K, float scale, int brow, int bcol,
        const float* __restrict__ att_s, const float* __restrict__ att_d,
        float* __restrict__ a_s, float* __restrict__ a_d, int H,
        const float* __restrict__ bnsc, const float* __restrict__ bnsh) {
    __shared__ _Float16 Ah[64][36];
    __shared__ _Float16 Bt[64][36];
    int tid  = threadIdx.x;
    int wave = tid >> 6, lane = tid & 63, lo16 = lane & 15, g = lane >> 4;
    f32x4 acc[4];
    #pragma unroll
    for (int i = 0; i < 4; ++i) acc[i] = (f32x4){0.f, 0.f, 0.f, 0.f};

    for (int k0 = 0; k0 < K; k0 += 32) {
        {   // stage A 64x32 -> f16 (optionally BN+ReLU fused)
            int r  = tid >> 2;
            int ks = (tid & 3) * 8;
            const float* ap = A + (size_t)(brow + r) * K + k0 + ks;
            f32x4 a0 = *(const f32x4*)ap;
            f32x4 a1 = *(const f32x4*)(ap + 4);
            if (BN) {
                #pragma unroll
                for (int i = 0; i < 4; ++i) {
                    int c0 = k0 + ks + i, c1 = c0 + 4;
                    a0[i] = fmaxf(a0[i] * bnsc[c0] + bnsh[c0], 0.f);
                    a1[i] = fmaxf(a1[i] * bnsc[c1] + bnsh[c1], 0.f);
                }
            }
            half4_t h0, h1;
            #pragma unroll
            for (int i = 0; i < 4; ++i) { h0[i] = (_Float16)a0[i]; h1[i] = (_Float16)a1[i]; }
            *(half4_t*)&Ah[r][ks]     = h0;
            *(half4_t*)&Ah[r][ks + 4] = h1;
        }
        if (TRANS_B) {   // B[Nc][K] -> Bt[n][k]
            int n  = tid >> 2;
            int ks = (tid & 3) * 8;
            const float* bp = B + (size_t)(bcol + n) * K + k0 + ks;
            f32x4 b0 = *(const f32x4*)bp;
            f32x4 b1 = *(const f32x4*)(bp + 4);
            half4_t h0, h1;
            #pragma unroll
            for (int i = 0; i < 4; ++i) { h0[i] = (_Float16)b0[i]; h1[i] = (_Float16)b1[i]; }
            *(half4_t*)&Bt[n][ks]     = h0;
            *(half4_t*)&Bt[n][ks + 4] = h1;
        } else {         // B[K][Nc] -> Bt[n][k] (transpose during staging)
            int n  = tid & 63;
            int kb = (tid >> 6) * 8;
            half4_t h0, h1;
            #pragma unroll
            for (int i = 0; i < 4; ++i)
                h0[i] = (_Float16)B[(size_t)(k0 + kb + i) * Nc + bcol + n];
            #pragma unroll
            for (int i = 0; i < 4; ++i)
                h1[i] = (_Float16)B[(size_t)(k0 + kb + 4 + i) * Nc + bcol + n];
            *(half4_t*)&Bt[n][kb]     = h0;
            *(half4_t*)&Bt[n][kb + 4] = h1;
        }
        __syncthreads();
        #pragma unroll
        for (int kh = 0; kh < 2; ++kh) {
            half4_t af = *(const half4_t*)&Ah[wave * 16 + lo16][kh * 16 + g * 4];
            #pragma unroll
            for (int cf = 0; cf < 4; ++cf) {
                half4_t bf = *(const half4_t*)&Bt[cf * 16 + lo16][kh * 16 + g * 4];
                acc[cf] = MFMA16(af, bf, acc[cf]);
            }
        }
        __syncthreads();
    }
    int rbase = brow + wave * 16 + g * 4;
    #pragma unroll
    for (int cf = 0; cf < 4; ++cf) {
        int c = bcol + cf * 16 + lo16;
        float bv = bias ? bias[c] : 0.f;
        #pragma unroll
        for (int reg = 0; reg < 4; ++reg) {
            float v = (acc[cf][reg] + bv) * scale;
            if (ACT == 1) v = fmaxf(v, 0.f);
            if (OUT_F16) ((_Float16*)Cout)[(size_t)(rbase + reg) * Nc + c] = (_Float16)v;
            else         ((float*)Cout)[(size_t)(rbase + reg) * Nc + c] = v;
        }
    }
    if (GAT) {
        float as_c[4], ad_c[4];
        #pragma unroll
        for (int cf = 0; cf < 4; ++cf) {
            int c = bcol + cf * 16 + lo16;
            as_c[cf] = att_s[c];
            ad_c[cf] = att_d[c];
        }
        int head = bcol >> 6;
        #pragma unroll
        for (int reg = 0; reg < 4; ++reg) {
            float ps = 0.f, pd = 0.f;
            #pragma unroll
            for (int cf = 0; cf < 4; ++cf) {
                ps += acc[cf][reg] * as_c[cf];
                pd += acc[cf][reg] * ad_c[cf];
            }
            #pragma unroll
            for (int off = 8; off; off >>= 1) {
                ps += __shfl_xor(ps, off);
                pd += __shfl_xor(pd, off);
            }
            if (lo16 == 0) {
                int row = rbase + reg;
                a_s[row * H + head] = ps;
                a_d[row * H + head] = pd;
            }
        }
    }
}

template<bool TRANS_B, bool OUT_F16, int ACT, bool GAT, bool BN>
__global__ void mfma_gemm(const float* __restrict__ A, const float* __restrict__ B,
                          const float* __restrict__ bias, void* __restrict__ Cout,
                          int M, int Nc, int K, float scale,
                          const float* __restrict__ att_s, const float* __restrict__ att_d,
                          float* __restrict__ a_s, float* __restrict__ a_d, int H,
                          const float* __restrict__ bnsc, const float* __restrict__ bnsh) {
    mfma_gemm_body<TRANS_B, OUT_F16, ACT, GAT, BN>(A, B, bias, Cout, M, Nc, K, scale,
                                                   blockIdx.y * 64, blockIdx.x * 64,
                                                   att_s, att_d, a_s, a_d, H, bnsc, bnsh);
}

// fused Q/K/V projection (BN of layer-2 fused into A): blockIdx.z selects slice
__global__ void qkv_gemm(const float* __restrict__ A,
                         const float* __restrict__ Wq, const float* __restrict__ Wk,
                         const float* __restrict__ Wv, const float* __restrict__ bq,
                         const float* __restrict__ bk, const float* __restrict__ bv,
                         _Float16* __restrict__ qh, _Float16* __restrict__ kh,
                         _Float16* __restrict__ vh, int M, float qscale,
                         const float* __restrict__ bnsc, const float* __restrict__ bnsh) {
    int z = blockIdx.z;
    const float* B    = z == 0 ? Wq : (z == 1 ? Wk : Wv);
    const float* bias = z == 0 ? bq : (z == 1 ? bk : bv);
    _Float16* Cout    = z == 0 ? qh : (z == 1 ? kh : vh);
    float scale       = z == 0 ? qscale : 1.f;
    mfma_gemm_body<true, true, 0, false, true>(A, B, bias, Cout, M, 64, 64, scale,
                                               blockIdx.y * 64, 0,
                                               nullptr, nullptr, nullptr, nullptr, 0,
                                               bnsc, bnsh);
}

// ------------------------------------------------------------------ GAT prep
__global__ void count_deg(const int* __restrict__ ei, int* __restrict__ deg, int E) {
    int e = blockIdx.x * 256 + threadIdx.x;
    if (e < E) atomicAdd(&deg[ei[E + e]], 1);   // ei[1] row = dst
}

// single block, 1024 threads, N=8192 (8 per thread); +1 per node = self-loop
__global__ void scan_deg(const int* __restrict__ deg, int* __restrict__ row_ptr,
                         int* __restrict__ cursor, int N) {
    __shared__ int tmp[1024];
    int tid = threadIdx.x;
    int base = tid * 8;
    int local[8];
    int s = 0;
    #pragma unroll
    for (int j = 0; j < 8; ++j) { local[j] = deg[base + j] + 1; s += local[j]; }
    tmp[tid] = s;
    __syncthreads();
    for (int off = 1; off < 1024; off <<= 1) {
        int add = (tid >= off) ? tmp[tid - off] : 0;
        __syncthreads();
        tmp[tid] += add;
        __syncthreads();
    }
    int run = tmp[tid] - s;   // exclusive prefix of this chunk
    #pragma unroll
    for (int j = 0; j < 8; ++j) {
        row_ptr[base + j] = run;
        cursor[base + j]  = run;
        run += local[j];
    }
    if (tid == 1023) row_ptr[N] = run;
}

__global__ void fill_csr(const int* __restrict__ ei, int* __restrict__ cursor,
                         int* __restrict__ col, int E, int N) {
    int e = blockIdx.x * 256 + threadIdx.x;
    if (e < E) {
        int dst = ei[E + e];
        int pos = atomicAdd(&cursor[dst], 1);
        col[pos] = ei[e];
    } else if (e < E + N) {
        int n = e - E;
        int pos = atomicAdd(&cursor[n], 1);
        col[pos] = n;
    }
}

// ---------------------------------------------------------------- GAT gather (H=8)
// Block = ONE node, 4 waves; wave w owns edges beg+w+4k (4-way edge split ->
// 32 waves/CU vs 2 before). Single-pass ONLINE per-wave softmax (no max
// pre-pass; rescale path cold since deg<=256 in practice). Per-edge: one
// 16B/lane load of the full 1KB h-row, broadcast weights via per-wave LDS
// stash. Deterministic fixed-order 4-way merge (fa5 pattern). No atomics.
__global__ __launch_bounds__(256) void gat_gather_h8(
        const _Float16* __restrict__ h, const float* __restrict__ a_s,
        const float* __restrict__ a_d, const int* __restrict__ row_ptr,
        const int* __restrict__ col, float* __restrict__ out, int N) {
    __shared__ float wsf[4][64][8];   // stash: per-edge w[8]; later: per-wave acc row
    __shared__ int   wsc[4][64];
    __shared__ float MD[4][2][8];     // per-wave m[8], den[8]
    int t = threadIdx.x, w = t >> 6, lane = t & 63;
    int n = blockIdx.x;
    int hd = lane >> 3;
    int beg = row_ptr[n], end = row_ptr[n + 1];
    int deg = end - beg;
    int cw = (deg - w + 3) >> 2;      // this wave's edge count (>=0; deg-w >= -2)
    float ad[8];
    #pragma unroll
    for (int i = 0; i < 8; ++i) ad[i] = a_d[n * 8 + i];
    float m[8], den[8], acc[8];
    #pragma unroll
    for (int i = 0; i < 8; ++i) { m[i] = -1e30f; den[i] = 0.f; acc[i] = 0.f; }
    const _Float16* hb = h + (size_t)lane * 8;

    for (int base = 0; base < cw; base += 64) {
        int k = base + lane;
        bool valid = k < cw;
        int cj = 0;
        float sc[8];
        #pragma unroll
        for (int i = 0; i < 8; ++i) sc[i] = -1e30f;
        if (valid) {
            cj = col[beg + w + 4 * k];
            f32x4 s0 = *(const f32x4*)(a_s + (size_t)cj * 8);
            f32x4 s1 = *(const f32x4*)(a_s + (size_t)cj * 8 + 4);
            #pragma unroll
            for (int i = 0; i < 4; ++i) {
                float sa = s0[i] + ad[i];
                sc[i] = sa > 0.f ? sa : 0.2f * sa;
                float sb = s1[i] + ad[4 + i];
                sc[4 + i] = sb > 0.f ? sb : 0.2f * sb;
            }
        }
        // chunk max per head
        float cm[8];
        #pragma unroll
        for (int i = 0; i < 8; ++i) {
            cm[i] = sc[i];
            #pragma unroll
            for (int off = 32; off; off >>= 1) cm[i] = fmaxf(cm[i], __shfl_xor(cm[i], off));
        }
        if (base > 0) {   // online rescale (cold: only deg>256 nodes)
            float r[8];
            #pragma unroll
            for (int i = 0; i < 8; ++i) {
                float mn = fmaxf(m[i], cm[i]);
                r[i] = __expf(m[i] - mn);
                den[i] *= r[i];
                m[i] = mn;
            }
            float rh = r[0];
            #pragma unroll
            for (int i = 1; i < 8; ++i) rh = (hd == i) ? r[i] : rh;
            #pragma unroll
            for (int i = 0; i < 8; ++i) acc[i] *= rh;
        } else {
            #pragma unroll
            for (int i = 0; i < 8; ++i) m[i] = cm[i];
        }
        float wv[8];
        #pragma unroll
        for (int i = 0; i < 8; ++i) {
            wv[i] = valid ? __expf(sc[i] - m[i]) : 0.f;
            den[i] += wv[i];
        }
        wsc[w][lane] = cj;
        *(f32x4*)&wsf[w][lane][0] = (f32x4){wv[0], wv[1], wv[2], wv[3]};
        *(f32x4*)&wsf[w][lane][4] = (f32x4){wv[4], wv[5], wv[6], wv[7]};
        int cnt = min(64, cw - base);
        #pragma unroll 4
        for (int k2 = 0; k2 < cnt; ++k2) {
            int ck   = wsc[w][k2];
            float wk = wsf[w][k2][hd];
            half8_t hv = *(const half8_t*)(hb + (size_t)ck * 512);
            #pragma unroll
            for (int i = 0; i < 8; ++i) acc[i] += wk * (float)hv[i];
        }
    }
    // reduce den across lanes (per head)
    #pragma unroll
    for (int i = 0; i < 8; ++i)
        #pragma unroll
        for (int off = 32; off; off >>= 1) den[i] += __shfl_xor(den[i], off);
    // publish partial state (own-wave LDS rows; no cross-wave use before barrier)
    *(f32x4*)&wsf[w][lane][0] = (f32x4){acc[0], acc[1], acc[2], acc[3]};
    *(f32x4*)&wsf[w][lane][4] = (f32x4){acc[4], acc[5], acc[6], acc[7]};
    if (lane == 0) {
        #pragma unroll
        for (int i = 0; i < 8; ++i) { MD[w][0][i] = m[i]; MD[w][1][i] = den[i]; }
    }
    __syncthreads();
    if (w == 0) {   // deterministic merge of waves 0..3
        float M = fmaxf(fmaxf(MD[0][0][hd], MD[1][0][hd]), fmaxf(MD[2][0][hd], MD[3][0][hd]));
        float f0 = __expf(MD[0][0][hd] - M);
        float f1 = __expf(MD[1][0][hd] - M);
        float f2 = __expf(MD[2][0][hd] - M);
        float f3 = __expf(MD[3][0][hd] - M);
        float D = MD[0][1][hd] * f0 + MD[1][1][hd] * f1 + MD[2][1][hd] * f2 + MD[3][1][hd] * f3;
        float y[8];
        #pragma unroll
        for (int i = 0; i < 8; ++i)
            y[i] = wsf[0][lane][i] * f0 + wsf[1][lane][i] * f1 +
                   wsf[2][lane][i] * f2 + wsf[3][lane][i] * f3;
        float inv = 1.f / ((D + 1e-16f) * 8.f);
        #pragma unroll
        for (int i = 0; i < 8; ++i) y[i] *= inv;
        #pragma unroll
        for (int i = 0; i < 8; ++i) {
            y[i] += __shfl_xor(y[i], 8);
            y[i] += __shfl_xor(y[i], 16);
            y[i] += __shfl_xor(y[i], 32);
        }
        if (lane < 8) {   // write channels lane*8 .. lane*8+7
            *(f32x4*)(out + (size_t)n * 64 + lane * 8)     = (f32x4){y[0], y[1], y[2], y[3]};
            *(f32x4*)(out + (size_t)n * 64 + lane * 8 + 4) = (f32x4){y[4], y[5], y[6], y[7]};
        }
    }
}

// ---------------------------------------------------------------- GAT gather (H=1)
// Same 4-way edge-split structure; lane = channel; plain store.
__global__ __launch_bounds__(256) void gat_gather_h1(
        const _Float16* __restrict__ h, const float* __restrict__ a_s,
        const float* __restrict__ a_d, const int* __restrict__ row_ptr,
        const int* __restrict__ col, float* __restrict__ out, int N) {
    __shared__ uint2 wc[4][64];
    __shared__ float wacc[4][64];
    __shared__ float MD1[4][2];
    int t = threadIdx.x, w = t >> 6, lane = t & 63;
    int n = blockIdx.x;
    int beg = row_ptr[n], end = row_ptr[n + 1];
    int deg = end - beg;
    int cw = (deg - w + 3) >> 2;
    float adn = a_d[n];
    float m = -1e30f, den = 0.f, acc = 0.f;
    const _Float16* hb = h + lane;

    for (int base = 0; base < cw; base += 64) {
        int k = base + lane;
        bool valid = k < cw;
        int cj = 0;
        float sc = -1e30f;
        if (valid) {
            cj = col[beg + w + 4 * k];
            float sa = a_s[cj] + adn;
            sc = sa > 0.f ? sa : 0.2f * sa;
        }
        float cm = sc;
        #pragma unroll
        for (int off = 32; off; off >>= 1) cm = fmaxf(cm, __shfl_xor(cm, off));
        if (base > 0) {
            float mn = fmaxf(m, cm);
            float r = __expf(m - mn);
            den *= r; acc *= r; m = mn;
        } else {
            m = cm;
        }
        float wv = valid ? __expf(sc - m) : 0.f;
        den += wv;
        uint2 p; p.x = __float_as_uint(wv); p.y = (unsigned)cj;
        wc[w][lane] = p;
        int cnt = min(64, cw - base);
        #pragma unroll 4
        for (int k2 = 0; k2 < cnt; ++k2) {
            uint2 q = wc[w][k2];
            acc += __uint_as_float(q.x) * (float)hb[(size_t)q.y * 64];
        }
    }
    #pragma unroll
    for (int off = 32; off; off >>= 1) den += __shfl_xor(den, off);
    wacc[w][lane] = acc;
    if (lane == 0) { MD1[w][0] = m; MD1[w][1] = den; }
    __syncthreads();
    if (w == 0) {
        float M = fmaxf(fmaxf(MD1[0][0], MD1[1][0]), fmaxf(MD1[2][0], MD1[3][0]));
        float D = 0.f, y = 0.f;
        #pragma unroll
        for (int w2 = 0; w2 < 4; ++w2) {
            float f = __expf(MD1[w2][0] - M);
            D += MD1[w2][1] * f;
            y += wacc[w2][lane] * f;
        }
        out[(size_t)n * 64 + lane] = y / (D + 1e-16f);
    }
}

// ------------------------------------------------------------------ BatchNorm stats
__global__ void bn_stats(const float* __restrict__ x, const float* __restrict__ gamma,
                         const float* __restrict__ beta, float* __restrict__ scale,
                         float* __restrict__ shift, int N) {
    int c = blockIdx.x;
    float s = 0.f, ss = 0.f;
    for (int r = threadIdx.x; r < N; r += 256) {
        float v = x[(size_t)r * 64 + c];
        s += v; ss += v * v;
    }
    #pragma unroll
    for (int off = 32; off; off >>= 1) {
        s  += __shfl_xor(s, off);
        ss += __shfl_xor(ss, off);
    }
    __shared__ float red[8];
    int wv = threadIdx.x >> 6, ln = threadIdx.x & 63;
    if (ln == 0) { red[wv] = s; red[4 + wv] = ss; }
    __syncthreads();
    if (threadIdx.x == 0) {
        float S  = red[0] + red[1] + red[2] + red[3];
        float SS = red[4] + red[5] + red[6] + red[7];
        float mu  = S / N;
        float var = SS / N - mu * mu;
        float istd = rsqrtf(var + 1e-5f);
        scale[c] = gamma[c] * istd;
        shift[c] = beta[c] - mu * gamma[c] * istd;
    }
}

// ------------------------------------------------------------------ MHA prep
// fused: vh [N][64] -> vt [64][N] (transpose) AND kh [N][64] -> khp [4][N][16]
__global__ void vkpack(const _Float16* __restrict__ vh, const _Float16* __restrict__ kh,
                       _Float16* __restrict__ vt, _Float16* __restrict__ khp, int N) {
    __shared__ _Float16 tile[64][68];
    int kb = blockIdx.x * 64;
    int t  = threadIdx.x;
    {
        int r = t >> 2, c0 = (t & 3) * 16;
        half8_t x0 = *(const half8_t*)(vh + (size_t)(kb + r) * 64 + c0);
        half8_t x1 = *(const half8_t*)(vh + (size_t)(kb + r) * 64 + c0 + 8);
        #pragma unroll
        for (int i = 0; i < 8; ++i) { tile[r][c0 + i] = x0[i]; tile[r][c0 + 8 + i] = x1[i]; }
    }
    // kpack (independent of the transpose; no sync needed yet)
    #pragma unroll
    for (int rep = 0; rep < 2; ++rep) {
        int l = t + 256 * rep;
        int n = kb + (l >> 3), c8 = (l & 7) * 8;
        half8_t v = *(const half8_t*)(kh + (size_t)n * 64 + c8);
        *(half8_t*)(khp + ((size_t)(c8 >> 4) * N + n) * 16 + (c8 & 15)) = v;
    }
    __syncthreads();
    {
        int c = t >> 2, ks = (t & 3) * 16;
        half8_t y0, y1;
        #pragma unroll
        for (int i = 0; i < 8; ++i) { y0[i] = tile[ks + i][c]; y1[i] = tile[ks + 8 + i][c]; }
        *(half8_t*)(vt + (size_t)c * N + kb + ks)     = y0;
        *(half8_t*)(vt + (size_t)c * N + kb + ks + 8) = y1;
    }
}

// Block = 8 waves / 512 thr, one head, 32 queries (2 q-subtiles x 4-way key split).
// Group grp (2 waves) processes tiles grp, grp+4, ... ; double-buffered LDS;
// exp2-domain softmax with defer-max; deterministic fixed-order 4-way merge.
__global__ __launch_bounds__(512) void mha_fa5(const _Float16* __restrict__ qh,
                                               const _Float16* __restrict__ khp,
                                               const _Float16* __restrict__ vt,
                                               float* __restrict__ ao, int N) {
    __shared__ alignas(16) char smem[38912];
    typedef _Float16 (*KtT)[2][64][20];   // [grp][buf][key][ch]   20480 B
    typedef _Float16 (*VtT)[2][16][68];   // [grp][buf][ch][key]   17408 B
    KtT Kt = (KtT)smem;
    VtT Vt = (VtT)(smem + 20480);
    float* MBp = (float*)(smem + 37888);  // [wsub][grp][2][16] = 1024 B
    float* OBp = (float*)smem;            // overlay on Kt: [wsub][grp][16][17] f32

    int h    = blockIdx.y;
    int t    = threadIdx.x;
    int lane = t & 63;
    int wave = t >> 6;
    int grp  = wave >> 1;
    int wsub = wave & 1;
    int lo16 = lane & 15;
    int g    = lane >> 4;
    int q    = blockIdx.x * 32 + wsub * 16 + lo16;

    half4_t qf = *(const half4_t*)(qh + (size_t)q * 64 + h * 16 + g * 4);
    const _Float16* kp = khp + (size_t)h * N * 16;
    const _Float16* vp = vt + (size_t)h * 16 * N;

    int gt   = t & 127;                   // thread id within the group (2 waves)
    int skey = gt >> 1, sch = (gt & 1) * 8;   // K staging: 16B per thread
    int sd   = gt >> 3, skv = (gt & 7) * 8;   // V staging: 16B per thread

    {   // prologue: stage this group's tile 0
        int kt = grp * 64;
        half8_t kv = *(const half8_t*)(kp + (size_t)(kt + skey) * 16 + sch);
        half8_t vv = *(const half8_t*)(vp + (size_t)sd * N + kt + skv);
        half4_t a, b, c, d;
        #pragma unroll
        for (int i = 0; i < 4; ++i) { a[i] = kv[i]; b[i] = kv[4 + i]; c[i] = vv[i]; d[i] = vv[4 + i]; }
        *(half4_t*)&Kt[grp][0][skey][sch]     = a;
        *(half4_t*)&Kt[grp][0][skey][sch + 4] = b;
        *(half4_t*)&Vt[grp][0][sd][skv]       = c;
        *(half4_t*)&Vt[grp][0][sd][skv + 4]   = d;
    }

    float m = -1e30f, l = 0.f;
    f32x4 o = {0.f, 0.f, 0.f, 0.f};
    const f32x4 zero = {0.f, 0.f, 0.f, 0.f};
    const int nit = N / 256;              // 4 groups x 64 keys

    for (int it = 0; it < nit; ++it) {
        int cur = it & 1;
        __syncthreads();
        if (it + 1 < nit) {
            int kt = ((it + 1) * 4 + grp) * 64;
            half8_t kv = *(const half8_t*)(kp + (size_t)(kt + skey) * 16 + sch);
            half8_t vv = *(const half8_t*)(vp + (size_t)sd * N + kt + skv);
            half4_t a, b, c, d;
            #pragma unroll
            for (int i = 0; i < 4; ++i) { a[i] = kv[i]; b[i] = kv[4 + i]; c[i] = vv[i]; d[i] = vv[4 + i]; }
            *(half4_t*)&Kt[grp][cur ^ 1][skey][sch]     = a;
            *(half4_t*)&Kt[grp][cur ^ 1][skey][sch + 4] = b;
            *(half4_t*)&Vt[grp][cur ^ 1][sd][skv]       = c;
            *(half4_t*)&Vt[grp][cur ^ 1][sd][skv + 4]   = d;
        }
        // ---- QK^T: 4 sub-tiles of 16 keys (scores in log2 domain)
        f32x4 s[4];
        __builtin_amdgcn_s_setprio(1);
        #pragma unroll
        for (int st = 0; st < 4; ++st) {
            half4_t kf = *(const half4_t*)&Kt[grp][cur][st * 16 + lo16][g * 4];
            s[st] = MFMA16(kf, qf, zero);
        }
        __builtin_amdgcn_s_setprio(0);
        // ---- online softmax, defer-max (THR=8 in log2 domain)
        float t0 = fmaxf(fmaxf(s[0][0], s[0][1]), s[0][2]);
        float t1 = fmaxf(fmaxf(s[0][3], s[1][0]), s[1][1]);
        float t2 = fmaxf(fmaxf(s[1][2], s[1][3]), s[2][0]);
        float t3 = fmaxf(fmaxf(s[2][1], s[2][2]), s[2][3]);
        float t4 = fmaxf(fmaxf(s[3][0], s[3][1]), fmaxf(s[3][2], s[3][3]));
        float tm = fmaxf(fmaxf(fmaxf(t0, t1), fmaxf(t2, t3)), t4);
        tm = fmaxf(tm, __shfl_xor(tm, 16));
        tm = fmaxf(tm, __shfl_xor(tm, 32));
        if (!__all(tm <= m + 8.f)) {
            float mnew = fmaxf(m, tm);
            float r = EXP2N(m - mnew);
            l *= r;
            #pragma unroll
            for (int i = 0; i < 4; ++i) o[i] *= r;
            m = mnew;
        }
        float lsum = 0.f;
        half4_t pf[4];
        #pragma unroll
        for (int st = 0; st < 4; ++st) {
            float p0 = EXP2N(s[st][0] - m);
            float p1 = EXP2N(s[st][1] - m);
            float p2 = EXP2N(s[st][2] - m);
            float p3 = EXP2N(s[st][3] - m);
            lsum += (p0 + p1) + (p2 + p3);
            auto lo = __builtin_amdgcn_cvt_pkrtz(p0, p1);   // __fp16x2
            auto hi = __builtin_amdgcn_cvt_pkrtz(p2, p3);
            pf[st][0] = (_Float16)lo[0]; pf[st][1] = (_Float16)lo[1];
            pf[st][2] = (_Float16)hi[0]; pf[st][3] = (_Float16)hi[1];
        }
        l += lsum;
        // ---- PV
        __builtin_amdgcn_s_setprio(1);
        #pragma unroll
        for (int st = 0; st < 4; ++st) {
            half4_t vf = *(const half4_t*)&Vt[grp][cur][lo16][st * 16 + g * 4];
            o = MFMA16(vf, pf[st], o);
        }
        __builtin_amdgcn_s_setprio(0);
    }
    // per-wave l reduce across the 4 lane-groups (disjoint key subsets)
    l += __shfl_xor(l, 16);
    l += __shfl_xor(l, 32);

    __syncthreads();   // all tile reads done -> safe to overlay merge buffers on Kt
    if (grp != 0) {    // publish partial state
        if (lane < 16) {
            MBp[((wsub * 4 + grp) * 2 + 0) * 16 + lane] = m;
            MBp[((wsub * 4 + grp) * 2 + 1) * 16 + lane] = l;
        }
        #pragma unroll
        for (int i = 0; i < 4; ++i)
            OBp[((wsub * 4 + grp) * 16 + g * 4 + i) * 17 + lo16] = o[i];
    }
    __syncthreads();
    if (grp == 0) {    // deterministic merge: grp 0,1,2,3 in fixed order
        float M = m, L = l;
        f32x4 O = o;
        #pragma unroll
        for (int gg = 1; gg < 4; ++gg) {
            float m1 = MBp[((wsub * 4 + gg) * 2 + 0) * 16 + lo16];
            float l1 = MBp[((wsub * 4 + gg) * 2 + 1) * 16 + lo16];
            float Mn = fmaxf(M, m1);
            float e0 = EXP2N(M - Mn), e1 = EXP2N(m1 - Mn);
            L = L * e0 + l1 * e1;
            #pragma unroll
            for (int i = 0; i < 4; ++i)
                O[i] = O[i] * e0 + OBp[((wsub * 4 + gg) * 16 + g * 4 + i) * 17 + lo16] * e1;
            M = Mn;
        }
        float inv = 1.f / L;
        f32x4 res;
        #pragma unroll
        for (int i = 0; i < 4; ++i) res[i] = O[i] * inv;
        *(f32x4*)(ao + (size_t)q * 64 + h * 16 + g * 4) = res;
    }
}

// ------------------------------------------------------------------ fused MLP head
// per 64-row block: S1 = ao@Wo^T+bo (64x64); S2 = relu(S1@Wc1^T+bc1) (64x32);
// out = S2@Wc2^T+bc2 (64x10). Intermediates stay in LDS.
__global__ void mlp_head(const float* __restrict__ ao,
                         const float* __restrict__ Wo, const float* __restrict__ bo,
                         const float* __restrict__ Wc1, const float* __restrict__ bc1,
                         const float* __restrict__ Wc2, const float* __restrict__ bc2,
                         float* __restrict__ outp, int N) {
    __shared__ _Float16 At[64][68];
    __shared__ _Float16 Bt[64][68];
    int t = threadIdx.x, wave = t >> 6, lane = t & 63, lo16 = lane & 15, g = lane >> 4;
    int brow = blockIdx.x * 64;
    const f32x4 zero = {0.f, 0.f, 0.f, 0.f};
    {   // stage At <- ao, Bt <- Wo (both 64x64 f32 -> f16)
        int r = t >> 2, c0 = (t & 3) * 16;
        const float* ap = ao + (size_t)(brow + r) * 64 + c0;
        const float* wp = Wo + (size_t)r * 64 + c0;
        #pragma unroll
        for (int j = 0; j < 16; j += 4) {
            f32x4 va = *(const f32x4*)(ap + j);
            f32x4 vw = *(const f32x4*)(wp + j);
            half4_t ha, hw;
            #pragma unroll
            for (int i = 0; i < 4; ++i) { ha[i] = (_Float16)va[i]; hw[i] = (_Float16)vw[i]; }
            *(half4_t*)&At[r][c0 + j] = ha;
            *(half4_t*)&Bt[r][c0 + j] = hw;
        }
    }
    __syncthreads();
    // ---- S1 = At @ Wo^T + bo
    f32x4 acc1[4];
    #pragma unroll
    for (int i = 0; i < 4; ++i) acc1[i] = zero;
    #pragma unroll
    for (int kc = 0; kc < 4; ++kc) {
        half4_t af = *(const half4_t*)&At[wave * 16 + lo16][kc * 16 + g * 4];
        #pragma unroll
        for (int cf = 0; cf < 4; ++cf) {
            half4_t bf = *(const half4_t*)&Bt[cf * 16 + lo16][kc * 16 + g * 4];
            acc1[cf] = MFMA16(af, bf, acc1[cf]);
        }
    }
    // write S1 back to the wave's own 16 rows of At (wave-local, no barrier needed)
    #pragma unroll
    for (int cf = 0; cf < 4; ++cf) {
        int c = cf * 16 + lo16;
        float bv = bo[c];
        #pragma unroll
        for (int reg = 0; reg < 4; ++reg)
            At[wave * 16 + g * 4 + reg][c] = (_Float16)(acc1[cf][reg] + bv);
    }
    __syncthreads();
    {   // restage Bt <- Wc1 (32x64)
        int r = t >> 2, c0 = (t & 3) * 16;
        if (r < 32) {
            const float* wp = Wc1 + (size_t)r * 64 + c0;
            #pragma unroll
            for (int j = 0; j < 16; j += 4) {
                f32x4 vw = *(const f32x4*)(wp + j);
                half4_t hw;
                #pragma unroll
                for (int i = 0; i < 4; ++i) hw[i] = (_Float16)vw[i];
                *(half4_t*)&Bt[r][c0 + j] = hw;
            }
        }
    }
    __syncthreads();
    // ---- S2 = relu(S1 @ Wc1^T + bc1), 64x32
    f32x4 acc2[2];
    acc2[0] = zero; acc2[1] = zero;
    #pragma unroll
    for (int kc = 0; kc < 4; ++kc) {
        half4_t af = *(const half4_t*)&At[wave * 16 + lo16][kc * 16 + g * 4];
        #pragma unroll
        for (int cf = 0; cf < 2; ++cf) {
            half4_t bf = *(const half4_t*)&Bt[cf * 16 + lo16][kc * 16 + g * 4];
            acc2[cf] = MFMA16(af, bf, acc2[cf]);
        }
    }
    #pragma unroll
    for (int cf = 0; cf < 2; ++cf) {
        int c = cf * 16 + lo16;
        float bv = bc1[c];
        #pragma unroll
        for (int reg = 0; reg < 4; ++reg)
            At[wave * 16 + g * 4 + reg][c] = (_Float16)fmaxf(acc2[cf][reg] + bv, 0.f);
    }
    __syncthreads();
    {   // restage Bt <- Wc2 (10x32, zero-pad rows 10..15)
        if (t < 32) {
            int r = t >> 1, c0 = (t & 1) * 16;
            half4_t hw;
            #pragma unroll
            for (int j = 0; j < 16; j += 4) {
                if (r < 10) {
                    f32x4 vw = *(const f32x4*)(Wc2 + (size_t)r * 32 + c0 + j);
                    #pragma unroll
                    for (int i = 0; i < 4; ++i) hw[i] = (_Float16)vw[i];
                } else {
                    #pragma unroll
                    for (int i = 0; i < 4; ++i) hw[i] = (_Float16)0.f;
                }
                *(half4_t*)&Bt[r][c0 + j] = hw;
            }
        }
    }
    __syncthreads();
    // ---- out = S2 @ Wc2^T + bc2, 64x10
    f32x4 acc3 = zero;
    #pragma unroll
    for (int kc = 0; kc < 2; ++kc) {
        half4_t af = *(const half4_t*)&At[wave * 16 + lo16][kc * 16 + g * 4];
        half4_t bf = *(const half4_t*)&Bt[lo16][kc * 16 + g * 4];
        acc3 = MFMA16(af, bf, acc3);
    }
    if (lo16 < 10) {
        float bv = bc2[lo16];
        #pragma unroll
        for (int reg = 0; reg < 4; ++reg) {
            int row = brow + wave * 16 + g * 4 + reg;
            outp[(size_t)row * 10 + lo16] = acc3[reg] + bv;
        }
    }
}

// ------------------------------------------------------------------- host side
extern "C" void kernel_launch(void* const* d_in, const int* in_sizes, int n_in,
                              void* d_out, int out_size, void* d_ws, size_t ws_size,
                              hipStream_t stream) {
    const int N = NN, E = EE;
    const float* x    = (const float*)d_in[0];
    const int*   ei   = (const int*)d_in[1];
    const float* W[3]   = {(const float*)d_in[2], (const float*)d_in[6], (const float*)d_in[10]};
    const float* as_[3] = {(const float*)d_in[3], (const float*)d_in[7], (const float*)d_in[11]};
    const float* ad_[3] = {(const float*)d_in[4], (const float*)d_in[8], (const float*)d_in[12]};
    const float* bn_g = (const float*)d_in[14];
    const float* bn_b = (const float*)d_in[15];
    const float* Wq = (const float*)d_in[16];
    const float* Wk = (const float*)d_in[17];
    const float* Wv = (const float*)d_in[18];
    const float* Wo = (const float*)d_in[19];
    const float* bq = (const float*)d_in[20];
    const float* bk = (const float*)d_in[21];
    const float* bv = (const float*)d_in[22];
    const float* bo = (const float*)d_in[23];
    const float* Wc1 = (const float*)d_in[24];
    const float* bc1 = (const float*)d_in[25];
    const float* Wc2 = (const float*)d_in[26];
    const float* bc2 = (const float*)d_in[27];

    char* ws = (char*)d_ws;
    _Float16* h16 = (_Float16*)(ws + 0);       // 8192*512*2 = 8,388,608 (GAT phase)
    _Float16* qh = (_Float16*)(ws + 9437184);  // 1,048,576 (MHA phase)
    _Float16* kh = (_Float16*)(ws + 10485760); // 1,048,576
    _Float16* vh = (_Float16*)(ws + 11534336); // 1,048,576
    _Float16* vt = (_Float16*)(ws + 12582912); // 1,048,576
    _Float16* khp = (_Float16*)(ws + 13631488);// 1,048,576
    float* a_s  = (float*)(ws + 16777216);     // 262,144
    float* a_d  = (float*)(ws + 17039360);     // 262,144
    int* row_ptr = (int*)(ws + 17301504);      // 33,024
    int* cursor  = (int*)(ws + 17334528);      // 32,768
    int* deg     = (int*)(ws + 17367296);      // 32,768
    int* col     = (int*)(ws + 17400064);      // 1,081,344
    float* g0   = (float*)(ws + 18481408);     // 2,097,152
    float* g1   = (float*)(ws + 20578560);     // 2,097,152
    float* ao   = (float*)(ws + 28967168);     // 2,097,152
    float* bnscale = (float*)(ws + 32112896);  // 64
    float* bnshift = bnscale + 64;             // 64

    // ---- CSR build (same graph all layers); self-loops via +1 in scan_deg
    hipMemsetAsync(deg, 0, (size_t)N * 4, stream);
    count_deg<<<(E + 255) / 256, 256, 0, stream>>>(ei, deg, E);
    scan_deg<<<1, 1024, 0, stream>>>(deg, row_ptr, cursor, N);
    fill_csr<<<(E + N + 255) / 256, 256, 0, stream>>>(ei, cursor, col, E, N);

    // ---- 3 GAT layers. gat_coef fused into GEMM epilogue; BN+ReLU of layer i
    // fused into layer i+1's (or qkv's) A-staging. No float atomics anywhere.
    // L0 (H=8, K=128, no BN on input x)
    mfma_gemm<false, true, 0, true, false><<<dim3(8, N / 64), 256, 0, stream>>>(
        x, W[0], nullptr, h16, N, 512, 128, 1.f, as_[0], ad_[0], a_s, a_d, 8, nullptr, nullptr);
    gat_gather_h8<<<N, 256, 0, stream>>>(h16, a_s, a_d, row_ptr, col, g0, N);
    bn_stats<<<64, 256, 0, stream>>>(g0, bn_g, bn_b, bnscale, bnshift, N);
    // L1 (H=8, K=64, BN0 fused)
    mfma_gemm<false, true, 0, true, true><<<dim3(8, N / 64), 256, 0, stream>>>(
        g0, W[1], nullptr, h16, N, 512, 64, 1.f, as_[1], ad_[1], a_s, a_d, 8, bnscale, bnshift);
    gat_gather_h8<<<N, 256, 0, stream>>>(h16, a_s, a_d, row_ptr, col, g1, N);
    bn_stats<<<64, 256, 0, stream>>>(g1, bn_g + 64, bn_b + 64, bnscale, bnshift, N);
    // L2 (H=1, K=64, BN1 fused); gather is plain-store -> g0 reusable
    mfma_gemm<false, true, 0, true, true><<<dim3(1, N / 64), 256, 0, stream>>>(
        g1, W[2], nullptr, h16, N, 64, 64, 1.f, as_[2], ad_[2], a_s, a_d, 1, bnscale, bnshift);
    gat_gather_h1<<<N, 256, 0, stream>>>(h16, a_s, a_d, row_ptr, col, g0, N);
    bn_stats<<<64, 256, 0, stream>>>(g0, bn_g + 128, bn_b + 128, bnscale, bnshift, N);

    // ---- MHA (4 heads, hd=16): QKV proj with BN2 fused; exp2-domain flash
    // Q scale = 0.25 (1/sqrt(hd)) * log2(e) -> softmax in exp2 domain
    qkv_gemm<<<dim3(1, N / 64, 3), 256, 0, stream>>>(
        g0, Wq, Wk, Wv, bq, bk, bv, qh, kh, vh, N, 0.36067376f, bnscale, bnshift);
    vkpack<<<N / 64, 256, 0, stream>>>(vh, kh, vt, khp, N);
    mha_fa5<<<dim3(N / 32, 4), 512, 0, stream>>>(qh, khp, vt, ao, N);

    // ---- fused output head: Wo -> relu(Wc1) -> Wc2
    mlp_head<<<N / 64, 256, 0, stream>>>(ao, Wo, bo, Wc1, bc1, Wc2, bc2, (float*)d_out, N);
}

// Round 14
// 263.974 us; speedup vs baseline: 1.1966x; 1.1966x over previous
//
#include <hip/hip_runtime.h>
#include <hip/hip_bf16.h>

#define NN 8192
#define EE 262144
#define HID 64

typedef _Float16 half4_t __attribute__((ext_vector_type(4)));
typedef _Float16 half8_t __attribute__((ext_vector_type(8)));
typedef float f32x4 __attribute__((ext_vector_type(4)));

extern "C" __device__ float __ocml_native_exp2_f32(float);
#define EXP2N(x) __ocml_native_exp2_f32(x)

#define MFMA16(a, b, c) __builtin_amdgcn_mfma_f32_16x16x16f16(a, b, c, 0, 0, 0)

// ---------------------------------------------------------------- MFMA GEMM body
// (f16 inputs staged in LDS, f32 acc). Fragment conventions as verified:
//   mfma(X,Y,C): D layout col=lane&15, row=4*(lane>>4)+reg; frag lane: [lane&15][4g+i]
// BN=true: A-staging applies y = relu(a*bnsc[c]+bnsh[c])  (c = K-dim index, K==64)
template<bool TRANS_B, bool OUT_F16, int ACT, bool GAT, bool BN>
__device__ __forceinline__ void mfma_gemm_body(
        const float* __restrict__ A, const float* __restrict__ B,
        const float* __restrict__ bias, void* __restrict__ Cout,
        int M, int Nc, int K, float scale, int brow, int bcol,
        const float* __restrict__ att_s, const float* __restrict__ att_d,
        float* __restrict__ a_s, float* __restrict__ a_d, int H,
        const float* __restrict__ bnsc, const float* __restrict__ bnsh) {
    __shared__ _Float16 Ah[64][36];
    __shared__ _Float16 Bt[64][36];
    int tid  = threadIdx.x;
    int wave = tid >> 6, lane = tid & 63, lo16 = lane & 15, g = lane >> 4;
    f32x4 acc[4];
    #pragma unroll
    for (int i = 0; i < 4; ++i) acc[i] = (f32x4){0.f, 0.f, 0.f, 0.f};

    for (int k0 = 0; k0 < K; k0 += 32) {
        {   // stage A 64x32 -> f16 (optionally BN+ReLU fused)
            int r  = tid >> 2;
            int ks = (tid & 3) * 8;
            const float* ap = A + (size_t)(brow + r) * K + k0 + ks;
            f32x4 a0 = *(const f32x4*)ap;
            f32x4 a1 = *(const f32x4*)(ap + 4);
            if (BN) {
                #pragma unroll
                for (int i = 0; i < 4; ++i) {
                    int c0 = k0 + ks + i, c1 = c0 + 4;
                    a0[i] = fmaxf(a0[i] * bnsc[c0] + bnsh[c0], 0.f);
                    a1[i] = fmaxf(a1[i] * bnsc[c1] + bnsh[c1], 0.f);
                }
            }
            half4_t h0, h1;
            #pragma unroll
            for (int i = 0; i < 4; ++i) { h0[i] = (_Float16)a0[i]; h1[i] = (_Float16)a1[i]; }
            *(half4_t*)&Ah[r][ks]     = h0;
            *(half4_t*)&Ah[r][ks + 4] = h1;
        }
        if (TRANS_B) {   // B[Nc][K] -> Bt[n][k]
            int n  = tid >> 2;
            int ks = (tid & 3) * 8;
            const float* bp = B + (size_t)(bcol + n) * K + k0 + ks;
            f32x4 b0 = *(const f32x4*)bp;
            f32x4 b1 = *(const f32x4*)(bp + 4);
            half4_t h0, h1;
            #pragma unroll
            for (int i = 0; i < 4; ++i) { h0[i] = (_Float16)b0[i]; h1[i] = (_Float16)b1[i]; }
            *(half4_t*)&Bt[n][ks]     = h0;
            *(half4_t*)&Bt[n][ks + 4] = h1;
        } else {         // B[K][Nc] -> Bt[n][k] (transpose during staging)
            int n  = tid & 63;
            int kb = (tid >> 6) * 8;
            half4_t h0, h1;
            #pragma unroll
            for (int i = 0; i < 4; ++i)
                h0[i] = (_Float16)B[(size_t)(k0 + kb + i) * Nc + bcol + n];
            #pragma unroll
            for (int i = 0; i < 4; ++i)
                h1[i] = (_Float16)B[(size_t)(k0 + kb + 4 + i) * Nc + bcol + n];
            *(half4_t*)&Bt[n][kb]     = h0;
            *(half4_t*)&Bt[n][kb + 4] = h1;
        }
        __syncthreads();
        #pragma unroll
        for (int kh = 0; kh < 2; ++kh) {
            half4_t af = *(const half4_t*)&Ah[wave * 16 + lo16][kh * 16 + g * 4];
            #pragma unroll
            for (int cf = 0; cf < 4; ++cf) {
                half4_t bf = *(const half4_t*)&Bt[cf * 16 + lo16][kh * 16 + g * 4];
                acc[cf] = MFMA16(af, bf, acc[cf]);
            }
        }
        __syncthreads();
    }
    int rbase = brow + wave * 16 + g * 4;
    #pragma unroll
    for (int cf = 0; cf < 4; ++cf) {
        int c = bcol + cf * 16 + lo16;
        float bv = bias ? bias[c] : 0.f;
        #pragma unroll
        for (int reg = 0; reg < 4; ++reg) {
            float v = (acc[cf][reg] + bv) * scale;
            if (ACT == 1) v = fmaxf(v, 0.f);
            if (OUT_F16) ((_Float16*)Cout)[(size_t)(rbase + reg) * Nc + c] = (_Float16)v;
            else         ((float*)Cout)[(size_t)(rbase + reg) * Nc + c] = v;
        }
    }
    if (GAT) {
        float as_c[4], ad_c[4];
        #pragma unroll
        for (int cf = 0; cf < 4; ++cf) {
            int c = bcol + cf * 16 + lo16;
            as_c[cf] = att_s[c];
            ad_c[cf] = att_d[c];
        }
        int head = bcol >> 6;
        #pragma unroll
        for (int reg = 0; reg < 4; ++reg) {
            float ps = 0.f, pd = 0.f;
            #pragma unroll
            for (int cf = 0; cf < 4; ++cf) {
                ps += acc[cf][reg] * as_c[cf];
                pd += acc[cf][reg] * ad_c[cf];
            }
            #pragma unroll
            for (int off = 8; off; off >>= 1) {
                ps += __shfl_xor(ps, off);
                pd += __shfl_xor(pd, off);
            }
            if (lo16 == 0) {
                int row = rbase + reg;
                a_s[row * H + head] = ps;
                a_d[row * H + head] = pd;
            }
        }
    }
}

template<bool TRANS_B, bool OUT_F16, int ACT, bool GAT, bool BN>
__global__ void mfma_gemm(const float* __restrict__ A, const float* __restrict__ B,
                          const float* __restrict__ bias, void* __restrict__ Cout,
                          int M, int Nc, int K, float scale,
                          const float* __restrict__ att_s, const float* __restrict__ att_d,
                          float* __restrict__ a_s, float* __restrict__ a_d, int H,
                          const float* __restrict__ bnsc, const float* __restrict__ bnsh) {
    mfma_gemm_body<TRANS_B, OUT_F16, ACT, GAT, BN>(A, B, bias, Cout, M, Nc, K, scale,
                                                   blockIdx.y * 64, blockIdx.x * 64,
                                                   att_s, att_d, a_s, a_d, H, bnsc, bnsh);
}

// fused Q/K/V projection (BN of layer-2 fused into A): blockIdx.z selects slice
__global__ void qkv_gemm(const float* __restrict__ A,
                         const float* __restrict__ Wq, const float* __restrict__ Wk,
                         const float* __restrict__ Wv, const float* __restrict__ bq,
                         const float* __restrict__ bk, const float* __restrict__ bv,
                         _Float16* __restrict__ qh, _Float16* __restrict__ kh,
                         _Float16* __restrict__ vh, int M, float qscale,
                         const float* __restrict__ bnsc, const float* __restrict__ bnsh) {
    int z = blockIdx.z;
    const float* B    = z == 0 ? Wq : (z == 1 ? Wk : Wv);
    const float* bias = z == 0 ? bq : (z == 1 ? bk : bv);
    _Float16* Cout    = z == 0 ? qh : (z == 1 ? kh : vh);
    float scale       = z == 0 ? qscale : 1.f;
    mfma_gemm_body<true, true, 0, false, true>(A, B, bias, Cout, M, 64, 64, scale,
                                               blockIdx.y * 64, 0,
                                               nullptr, nullptr, nullptr, nullptr, 0,
                                               bnsc, bnsh);
}

// ------------------------------------------------------------------ GAT prep
__global__ void count_deg(const int* __restrict__ ei, int* __restrict__ deg, int E) {
    int e = blockIdx.x * 256 + threadIdx.x;
    if (e < E) atomicAdd(&deg[ei[E + e]], 1);   // ei[1] row = dst
}

// single block, 1024 threads, N=8192 (8 per thread); +1 per node = self-loop
__global__ void scan_deg(const int* __restrict__ deg, int* __restrict__ row_ptr,
                         int* __restrict__ cursor, int N) {
    __shared__ int tmp[1024];
    int tid = threadIdx.x;
    int base = tid * 8;
    int local[8];
    int s = 0;
    #pragma unroll
    for (int j = 0; j < 8; ++j) { local[j] = deg[base + j] + 1; s += local[j]; }
    tmp[tid] = s;
    __syncthreads();
    for (int off = 1; off < 1024; off <<= 1) {
        int add = (tid >= off) ? tmp[tid - off] : 0;
        __syncthreads();
        tmp[tid] += add;
        __syncthreads();
    }
    int run = tmp[tid] - s;   // exclusive prefix of this chunk
    #pragma unroll
    for (int j = 0; j < 8; ++j) {
        row_ptr[base + j] = run;
        cursor[base + j]  = run;
        run += local[j];
    }
    if (tid == 1023) row_ptr[N] = run;
}

__global__ void fill_csr(const int* __restrict__ ei, int* __restrict__ cursor,
                         int* __restrict__ col, int E, int N) {
    int e = blockIdx.x * 256 + threadIdx.x;
    if (e < E) {
        int dst = ei[E + e];
        int pos = atomicAdd(&cursor[dst], 1);
        col[pos] = ei[e];
    } else if (e < E + N) {
        int n = e - E;
        int pos = atomicAdd(&cursor[n], 1);
        col[pos] = n;
    }
}

// ---------------------------------------------------------------- GAT gather (H=8)
// WAVE PER DST NODE, all 8 heads at once (grid N/4 x 4 waves = 8192 waves = full
// device capacity). lane = (head l>>3, chan-slice l&7). Per edge: ONE 16B/lane
// load of the full 1KB h-row; weights stashed per-wave in LDS and broadcast.
// No atomics, full overwrite. (Round-13 edge-split variant regressed: per-wave
// fixed reduction cost amortized over 4x fewer edges — do not re-split.)
__global__ void gat_gather_h8(const _Float16* __restrict__ h, const float* __restrict__ a_s,
                              const float* __restrict__ a_d, const int* __restrict__ row_ptr,
                              const int* __restrict__ col, float* __restrict__ out, int N) {
    __shared__ float wsf[4][64][8];
    __shared__ int   wsc[4][64];
    int t = threadIdx.x, wave = t >> 6, lane = t & 63;
    int n = (blockIdx.x * 256 + t) >> 6;
    int hd = lane >> 3;
    int beg = row_ptr[n], end = row_ptr[n + 1];
    float ad[8];
    #pragma unroll
    for (int i = 0; i < 8; ++i) ad[i] = a_d[n * 8 + i];   // wave-uniform scalars
    // ---- pass 1: per-head max
    float m[8];
    #pragma unroll
    for (int i = 0; i < 8; ++i) m[i] = -1e30f;
    for (int j = beg + lane; j < end; j += 64) {
        int c = col[j];
        f32x4 s0 = *(const f32x4*)(a_s + (size_t)c * 8);
        f32x4 s1 = *(const f32x4*)(a_s + (size_t)c * 8 + 4);
        #pragma unroll
        for (int i = 0; i < 4; ++i) {
            float sa = s0[i] + ad[i];
            sa = sa > 0.f ? sa : 0.2f * sa;
            m[i] = fmaxf(m[i], sa);
            float sb = s1[i] + ad[4 + i];
            sb = sb > 0.f ? sb : 0.2f * sb;
            m[4 + i] = fmaxf(m[4 + i], sb);
        }
    }
    #pragma unroll
    for (int i = 0; i < 8; ++i)
        #pragma unroll
        for (int off = 32; off; off >>= 1) m[i] = fmaxf(m[i], __shfl_xor(m[i], off));
    // ---- pass 2: weights + dense row gather
    const _Float16* hb = h + (size_t)lane * 8;
    float acc[8] = {0.f, 0.f, 0.f, 0.f, 0.f, 0.f, 0.f, 0.f};
    float den[8] = {0.f, 0.f, 0.f, 0.f, 0.f, 0.f, 0.f, 0.f};
    for (int base = beg; base < end; base += 64) {
        int j = base + lane;
        int cj = 0;
        float w[8];
        #pragma unroll
        for (int i = 0; i < 8; ++i) w[i] = 0.f;
        if (j < end) {
            cj = col[j];
            f32x4 s0 = *(const f32x4*)(a_s + (size_t)cj * 8);
            f32x4 s1 = *(const f32x4*)(a_s + (size_t)cj * 8 + 4);
            #pragma unroll
            for (int i = 0; i < 4; ++i) {
                float sa = s0[i] + ad[i];
                sa = sa > 0.f ? sa : 0.2f * sa;
                w[i] = __expf(sa - m[i]);
                den[i] += w[i];
                float sb = s1[i] + ad[4 + i];
                sb = sb > 0.f ? sb : 0.2f * sb;
                w[4 + i] = __expf(sb - m[4 + i]);
                den[4 + i] += w[4 + i];
            }
        }
        wsc[wave][lane] = cj;
        *(f32x4*)&wsf[wave][lane][0] = (f32x4){w[0], w[1], w[2], w[3]};
        *(f32x4*)&wsf[wave][lane][4] = (f32x4){w[4], w[5], w[6], w[7]};
        int cnt = min(64, end - base);
        #pragma unroll 4
        for (int k = 0; k < cnt; ++k) {
            int ck  = wsc[wave][k];                      // uniform broadcast
            float wk = wsf[wave][k][hd];                 // per-head broadcast
            half8_t hv = *(const half8_t*)(hb + (size_t)ck * 512);
            #pragma unroll
            for (int i = 0; i < 8; ++i) acc[i] += wk * (float)hv[i];
        }
    }
    #pragma unroll
    for (int i = 0; i < 8; ++i)
        #pragma unroll
        for (int off = 32; off; off >>= 1) den[i] += __shfl_xor(den[i], off);
    float inv = 1.f / ((den[hd] + 1e-16f) * 8.f);
    float y[8];
    #pragma unroll
    for (int i = 0; i < 8; ++i) y[i] = acc[i] * inv;
    #pragma unroll
    for (int i = 0; i < 8; ++i) {
        y[i] += __shfl_xor(y[i], 8);
        y[i] += __shfl_xor(y[i], 16);
        y[i] += __shfl_xor(y[i], 32);
    }
    if (lane < 8) {   // hd==0, sub==lane: write channels lane*8 .. lane*8+7
        *(f32x4*)(out + (size_t)n * 64 + lane * 8)     = (f32x4){y[0], y[1], y[2], y[3]};
        *(f32x4*)(out + (size_t)n * 64 + lane * 8 + 4) = (f32x4){y[4], y[5], y[6], y[7]};
    }
}

// ---------------------------------------------------------------- GAT gather (H=1)
// wave per node, single head -> plain store, no atomics, no pre-zero.
__global__ void gat_gather_h1(const _Float16* __restrict__ h, const float* __restrict__ a_s,
                              const float* __restrict__ a_d, const int* __restrict__ row_ptr,
                              const int* __restrict__ col, float* __restrict__ out, int N) {
    __shared__ uint2 wc[4][64];
    int t    = threadIdx.x;
    int wave = t >> 6;
    int lane = t & 63;
    int n    = (blockIdx.x * 256 + t) >> 6;
    int beg = row_ptr[n], end = row_ptr[n + 1];
    float adn = a_d[n];
    float m = -1e30f;
    for (int j = beg + lane; j < end; j += 64) {
        float sc = a_s[col[j]] + adn;
        sc = sc > 0.f ? sc : 0.2f * sc;
        m = fmaxf(m, sc);
    }
    #pragma unroll
    for (int off = 32; off; off >>= 1) m = fmaxf(m, __shfl_xor(m, off));
    const _Float16* hb = h + lane;
    float denom = 0.f;
    float acc0 = 0.f, acc1 = 0.f, acc2 = 0.f, acc3 = 0.f;
    float acc4 = 0.f, acc5 = 0.f, acc6 = 0.f, acc7 = 0.f;
    for (int base = beg; base < end; base += 64) {
        int j = base + lane;
        float w = 0.f; int s = 0;
        if (j < end) {
            s = col[j];
            float sc = a_s[s] + adn;
            sc = sc > 0.f ? sc : 0.2f * sc;
            w = __expf(sc - m);
        }
        denom += w;
        uint2 p; p.x = __float_as_uint(w); p.y = (unsigned)s;
        wc[wave][lane] = p;   // same-wave DS ops are in-order; no barrier needed
        int cnt = min(64, end - base);
        int k = 0;
        for (; k + 8 <= cnt; k += 8) {
            uint2 p0 = wc[wave][k];
            uint2 p1 = wc[wave][k + 1];
            uint2 p2 = wc[wave][k + 2];
            uint2 p3 = wc[wave][k + 3];
            uint2 p4 = wc[wave][k + 4];
            uint2 p5 = wc[wave][k + 5];
            uint2 p6 = wc[wave][k + 6];
            uint2 p7 = wc[wave][k + 7];
            acc0 += __uint_as_float(p0.x) * (float)hb[(size_t)p0.y * 64];
            acc1 += __uint_as_float(p1.x) * (float)hb[(size_t)p1.y * 64];
            acc2 += __uint_as_float(p2.x) * (float)hb[(size_t)p2.y * 64];
            acc3 += __uint_as_float(p3.x) * (float)hb[(size_t)p3.y * 64];
            acc4 += __uint_as_float(p4.x) * (float)hb[(size_t)p4.y * 64];
            acc5 += __uint_as_float(p5.x) * (float)hb[(size_t)p5.y * 64];
            acc6 += __uint_as_float(p6.x) * (float)hb[(size_t)p6.y * 64];
            acc7 += __uint_as_float(p7.x) * (float)hb[(size_t)p7.y * 64];
        }
        for (; k < cnt; ++k) {
            uint2 p0 = wc[wave][k];
            acc0 += __uint_as_float(p0.x) * (float)hb[(size_t)p0.y * 64];
        }
    }
    float acc = ((acc0 + acc1) + (acc2 + acc3)) + ((acc4 + acc5) + (acc6 + acc7));
    #pragma unroll
    for (int off = 32; off; off >>= 1) denom += __shfl_xor(denom, off);
    out[(size_t)n * 64 + lane] = acc / (denom + 1e-16f);
}

// ------------------------------------------------------------------ BatchNorm stats
__global__ void bn_stats(const float* __restrict__ x, const float* __restrict__ gamma,
                         const float* __restrict__ beta, float* __restrict__ scale,
                         float* __restrict__ shift, int N) {
    int c = blockIdx.x;
    float s = 0.f, ss = 0.f;
    for (int r = threadIdx.x; r < N; r += 256) {
        float v = x[(size_t)r * 64 + c];
        s += v; ss += v * v;
    }
    #pragma unroll
    for (int off = 32; off; off >>= 1) {
        s  += __shfl_xor(s, off);
        ss += __shfl_xor(ss, off);
    }
    __shared__ float red[8];
    int wv = threadIdx.x >> 6, ln = threadIdx.x & 63;
    if (ln == 0) { red[wv] = s; red[4 + wv] = ss; }
    __syncthreads();
    if (threadIdx.x == 0) {
        float S  = red[0] + red[1] + red[2] + red[3];
        float SS = red[4] + red[5] + red[6] + red[7];
        float mu  = S / N;
        float var = SS / N - mu * mu;
        float istd = rsqrtf(var + 1e-5f);
        scale[c] = gamma[c] * istd;
        shift[c] = beta[c] - mu * gamma[c] * istd;
    }
}

// ------------------------------------------------------------------ MHA prep
// fused: vh [N][64] -> vt [64][N] (transpose) AND kh [N][64] -> khp [4][N][16]
__global__ void vkpack(const _Float16* __restrict__ vh, const _Float16* __restrict__ kh,
                       _Float16* __restrict__ vt, _Float16* __restrict__ khp, int N) {
    __shared__ _Float16 tile[64][68];
    int kb = blockIdx.x * 64;
    int t  = threadIdx.x;
    {
        int r = t >> 2, c0 = (t & 3) * 16;
        half8_t x0 = *(const half8_t*)(vh + (size_t)(kb + r) * 64 + c0);
        half8_t x1 = *(const half8_t*)(vh + (size_t)(kb + r) * 64 + c0 + 8);
        #pragma unroll
        for (int i = 0; i < 8; ++i) { tile[r][c0 + i] = x0[i]; tile[r][c0 + 8 + i] = x1[i]; }
    }
    // kpack (independent of the transpose; no sync needed yet)
    #pragma unroll
    for (int rep = 0; rep < 2; ++rep) {
        int l = t + 256 * rep;
        int n = kb + (l >> 3), c8 = (l & 7) * 8;
        half8_t v = *(const half8_t*)(kh + (size_t)n * 64 + c8);
        *(half8_t*)(khp + ((size_t)(c8 >> 4) * N + n) * 16 + (c8 & 15)) = v;
    }
    __syncthreads();
    {
        int c = t >> 2, ks = (t & 3) * 16;
        half8_t y0, y1;
        #pragma unroll
        for (int i = 0; i < 8; ++i) { y0[i] = tile[ks + i][c]; y1[i] = tile[ks + 8 + i][c]; }
        *(half8_t*)(vt + (size_t)c * N + kb + ks)     = y0;
        *(half8_t*)(vt + (size_t)c * N + kb + ks + 8) = y1;
    }
}

// Block = 8 waves / 512 thr, one head, 32 queries (2 q-subtiles x 4-way key split).
// Group grp (2 waves) processes tiles grp, grp+4, ... ; double-buffered LDS;
// exp2-domain softmax with defer-max; deterministic fixed-order 4-way merge.
__global__ __launch_bounds__(512) void mha_fa5(const _Float16* __restrict__ qh,
                                               const _Float16* __restrict__ khp,
                                               const _Float16* __restrict__ vt,
                                               float* __restrict__ ao, int N) {
    __shared__ alignas(16) char smem[38912];
    typedef _Float16 (*KtT)[2][64][20];   // [grp][buf][key][ch]   20480 B
    typedef _Float16 (*VtT)[2][16][68];   // [grp][buf][ch][key]   17408 B
    KtT Kt = (KtT)smem;
    VtT Vt = (VtT)(smem + 20480);
    float* MBp = (float*)(smem + 37888);  // [wsub][grp][2][16] = 1024 B
    float* OBp = (float*)smem;            // overlay on Kt: [wsub][grp][16][17] f32

    int h    = blockIdx.y;
    int t    = threadIdx.x;
    int lane = t & 63;
    int wave = t >> 6;
    int grp  = wave >> 1;
    int wsub = wave & 1;
    int lo16 = lane & 15;
    int g    = lane >> 4;
    int q    = blockIdx.x * 32 + wsub * 16 + lo16;

    half4_t qf = *(const half4_t*)(qh + (size_t)q * 64 + h * 16 + g * 4);
    const _Float16* kp = khp + (size_t)h * N * 16;
    const _Float16* vp = vt + (size_t)h * 16 * N;

    int gt   = t & 127;                   // thread id within the group (2 waves)
    int skey = gt >> 1, sch = (gt & 1) * 8;   // K staging: 16B per thread
    int sd   = gt >> 3, skv = (gt & 7) * 8;   // V staging: 16B per thread

    {   // prologue: stage this group's tile 0
        int kt = grp * 64;
        half8_t kv = *(const half8_t*)(kp + (size_t)(kt + skey) * 16 + sch);
        half8_t vv = *(const half8_t*)(vp + (size_t)sd * N + kt + skv);
        half4_t a, b, c, d;
        #pragma unroll
        for (int i = 0; i < 4; ++i) { a[i] = kv[i]; b[i] = kv[4 + i]; c[i] = vv[i]; d[i] = vv[4 + i]; }
        *(half4_t*)&Kt[grp][0][skey][sch]     = a;
        *(half4_t*)&Kt[grp][0][skey][sch + 4] = b;
        *(half4_t*)&Vt[grp][0][sd][skv]       = c;
        *(half4_t*)&Vt[grp][0][sd][skv + 4]   = d;
    }

    float m = -1e30f, l = 0.f;
    f32x4 o = {0.f, 0.f, 0.f, 0.f};
    const f32x4 zero = {0.f, 0.f, 0.f, 0.f};
    const int nit = N / 256;              // 4 groups x 64 keys

    for (int it = 0; it < nit; ++it) {
        int cur = it & 1;
        __syncthreads();
        if (it + 1 < nit) {
            int kt = ((it + 1) * 4 + grp) * 64;
            half8_t kv = *(const half8_t*)(kp + (size_t)(kt + skey) * 16 + sch);
            half8_t vv = *(const half8_t*)(vp + (size_t)sd * N + kt + skv);
            half4_t a, b, c, d;
            #pragma unroll
            for (int i = 0; i < 4; ++i) { a[i] = kv[i]; b[i] = kv[4 + i]; c[i] = vv[i]; d[i] = vv[4 + i]; }
            *(half4_t*)&Kt[grp][cur ^ 1][skey][sch]     = a;
            *(half4_t*)&Kt[grp][cur ^ 1][skey][sch + 4] = b;
            *(half4_t*)&Vt[grp][cur ^ 1][sd][skv]       = c;
            *(half4_t*)&Vt[grp][cur ^ 1][sd][skv + 4]   = d;
        }
        // ---- QK^T: 4 sub-tiles of 16 keys (scores in log2 domain)
        f32x4 s[4];
        __builtin_amdgcn_s_setprio(1);
        #pragma unroll
        for (int st = 0; st < 4; ++st) {
            half4_t kf = *(const half4_t*)&Kt[grp][cur][st * 16 + lo16][g * 4];
            s[st] = MFMA16(kf, qf, zero);
        }
        __builtin_amdgcn_s_setprio(0);
        // ---- online softmax, defer-max (THR=8 in log2 domain)
        float t0 = fmaxf(fmaxf(s[0][0], s[0][1]), s[0][2]);
        float t1 = fmaxf(fmaxf(s[0][3], s[1][0]), s[1][1]);
        float t2 = fmaxf(fmaxf(s[1][2], s[1][3]), s[2][0]);
        float t3 = fmaxf(fmaxf(s[2][1], s[2][2]), s[2][3]);
        float t4 = fmaxf(fmaxf(s[3][0], s[3][1]), fmaxf(s[3][2], s[3][3]));
        float tm = fmaxf(fmaxf(fmaxf(t0, t1), fmaxf(t2, t3)), t4);
        tm = fmaxf(tm, __shfl_xor(tm, 16));
        tm = fmaxf(tm, __shfl_xor(tm, 32));
        if (!__all(tm <= m + 8.f)) {
            float mnew = fmaxf(m, tm);
            float r = EXP2N(m - mnew);
            l *= r;
            #pragma unroll
            for (int i = 0; i < 4; ++i) o[i] *= r;
            m = mnew;
        }
        float lsum = 0.f;
        half4_t pf[4];
        #pragma unroll
        for (int st = 0; st < 4; ++st) {
            float p0 = EXP2N(s[st][0] - m);
            float p1 = EXP2N(s[st][1] - m);
            float p2 = EXP2N(s[st][2] - m);
            float p3 = EXP2N(s[st][3] - m);
            lsum += (p0 + p1) + (p2 + p3);
            auto lo = __builtin_amdgcn_cvt_pkrtz(p0, p1);   // __fp16x2
            auto hi = __builtin_amdgcn_cvt_pkrtz(p2, p3);
            pf[st][0] = (_Float16)lo[0]; pf[st][1] = (_Float16)lo[1];
            pf[st][2] = (_Float16)hi[0]; pf[st][3] = (_Float16)hi[1];
        }
        l += lsum;
        // ---- PV
        __builtin_amdgcn_s_setprio(1);
        #pragma unroll
        for (int st = 0; st < 4; ++st) {
            half4_t vf = *(const half4_t*)&Vt[grp][cur][lo16][st * 16 + g * 4];
            o = MFMA16(vf, pf[st], o);
        }
        __builtin_amdgcn_s_setprio(0);
    }
    // per-wave l reduce across the 4 lane-groups (disjoint key subsets)
    l += __shfl_xor(l, 16);
    l += __shfl_xor(l, 32);

    __syncthreads();   // all tile reads done -> safe to overlay merge buffers on Kt
    if (grp != 0) {    // publish partial state
        if (lane < 16) {
            MBp[((wsub * 4 + grp) * 2 + 0) * 16 + lane] = m;
            MBp[((wsub * 4 + grp) * 2 + 1) * 16 + lane] = l;
        }
        #pragma unroll
        for (int i = 0; i < 4; ++i)
            OBp[((wsub * 4 + grp) * 16 + g * 4 + i) * 17 + lo16] = o[i];
    }
    __syncthreads();
    if (grp == 0) {    // deterministic merge: grp 0,1,2,3 in fixed order
        float M = m, L = l;
        f32x4 O = o;
        #pragma unroll
        for (int gg = 1; gg < 4; ++gg) {
            float m1 = MBp[((wsub * 4 + gg) * 2 + 0) * 16 + lo16];
            float l1 = MBp[((wsub * 4 + gg) * 2 + 1) * 16 + lo16];
            float Mn = fmaxf(M, m1);
            float e0 = EXP2N(M - Mn), e1 = EXP2N(m1 - Mn);
            L = L * e0 + l1 * e1;
            #pragma unroll
            for (int i = 0; i < 4; ++i)
                O[i] = O[i] * e0 + OBp[((wsub * 4 + gg) * 16 + g * 4 + i) * 17 + lo16] * e1;
            M = Mn;
        }
        float inv = 1.f / L;
        f32x4 res;
        #pragma unroll
        for (int i = 0; i < 4; ++i) res[i] = O[i] * inv;
        *(f32x4*)(ao + (size_t)q * 64 + h * 16 + g * 4) = res;
    }
}

// ------------------------------------------------------------------ fused MLP head
// per 64-row block: S1 = ao@Wo^T+bo (64x64); S2 = relu(S1@Wc1^T+bc1) (64x32);
// out = S2@Wc2^T+bc2 (64x10). Intermediates stay in LDS.
__global__ void mlp_head(const float* __restrict__ ao,
                         const float* __restrict__ Wo, const float* __restrict__ bo,
                         const float* __restrict__ Wc1, const float* __restrict__ bc1,
                         const float* __restrict__ Wc2, const float* __restrict__ bc2,
                         float* __restrict__ outp, int N) {
    __shared__ _Float16 At[64][68];
    __shared__ _Float16 Bt[64][68];
    int t = threadIdx.x, wave = t >> 6, lane = t & 63, lo16 = lane & 15, g = lane >> 4;
    int brow = blockIdx.x * 64;
    const f32x4 zero = {0.f, 0.f, 0.f, 0.f};
    {   // stage At <- ao, Bt <- Wo (both 64x64 f32 -> f16)
        int r = t >> 2, c0 = (t & 3) * 16;
        const float* ap = ao + (size_t)(brow + r) * 64 + c0;
        const float* wp = Wo + (size_t)r * 64 + c0;
        #pragma unroll
        for (int j = 0; j < 16; j += 4) {
            f32x4 va = *(const f32x4*)(ap + j);
            f32x4 vw = *(const f32x4*)(wp + j);
            half4_t ha, hw;
            #pragma unroll
            for (int i = 0; i < 4; ++i) { ha[i] = (_Float16)va[i]; hw[i] = (_Float16)vw[i]; }
            *(half4_t*)&At[r][c0 + j] = ha;
            *(half4_t*)&Bt[r][c0 + j] = hw;
        }
    }
    __syncthreads();
    // ---- S1 = At @ Wo^T + bo
    f32x4 acc1[4];
    #pragma unroll
    for (int i = 0; i < 4; ++i) acc1[i] = zero;
    #pragma unroll
    for (int kc = 0; kc < 4; ++kc) {
        half4_t af = *(const half4_t*)&At[wave * 16 + lo16][kc * 16 + g * 4];
        #pragma unroll
        for (int cf = 0; cf < 4; ++cf) {
            half4_t bf = *(const half4_t*)&Bt[cf * 16 + lo16][kc * 16 + g * 4];
            acc1[cf] = MFMA16(af, bf, acc1[cf]);
        }
    }
    // write S1 back to the wave's own 16 rows of At (wave-local, no barrier needed)
    #pragma unroll
    for (int cf = 0; cf < 4; ++cf) {
        int c = cf * 16 + lo16;
        float bv = bo[c];
        #pragma unroll
        for (int reg = 0; reg < 4; ++reg)
            At[wave * 16 + g * 4 + reg][c] = (_Float16)(acc1[cf][reg] + bv);
    }
    __syncthreads();
    {   // restage Bt <- Wc1 (32x64)
        int r = t >> 2, c0 = (t & 3) * 16;
        if (r < 32) {
            const float* wp = Wc1 + (size_t)r * 64 + c0;
            #pragma unroll
            for (int j = 0; j < 16; j += 4) {
                f32x4 vw = *(const f32x4*)(wp + j);
                half4_t hw;
                #pragma unroll
                for (int i = 0; i < 4; ++i) hw[i] = (_Float16)vw[i];
                *(half4_t*)&Bt[r][c0 + j] = hw;
            }
        }
    }
    __syncthreads();
    // ---- S2 = relu(S1 @ Wc1^T + bc1), 64x32
    f32x4 acc2[2];
    acc2[0] = zero; acc2[1] = zero;
    #pragma unroll
    for (int kc = 0; kc < 4; ++kc) {
        half4_t af = *(const half4_t*)&At[wave * 16 + lo16][kc * 16 + g * 4];
        #pragma unroll
        for (int cf = 0; cf < 2; ++cf) {
            half4_t bf = *(const half4_t*)&Bt[cf * 16 + lo16][kc * 16 + g * 4];
            acc2[cf] = MFMA16(af, bf, acc2[cf]);
        }
    }
    #pragma unroll
    for (int cf = 0; cf < 2; ++cf) {
        int c = cf * 16 + lo16;
        float bv = bc1[c];
        #pragma unroll
        for (int reg = 0; reg < 4; ++reg)
            At[wave * 16 + g * 4 + reg][c] = (_Float16)fmaxf(acc2[cf][reg] + bv, 0.f);
    }
    __syncthreads();
    {   // restage Bt <- Wc2 (10x32, zero-pad rows 10..15)
        if (t < 32) {
            int r = t >> 1, c0 = (t & 1) * 16;
            half4_t hw;
            #pragma unroll
            for (int j = 0; j < 16; j += 4) {
                if (r < 10) {
                    f32x4 vw = *(const f32x4*)(Wc2 + (size_t)r * 32 + c0 + j);
                    #pragma unroll
                    for (int i = 0; i < 4; ++i) hw[i] = (_Float16)vw[i];
                } else {
                    #pragma unroll
                    for (int i = 0; i < 4; ++i) hw[i] = (_Float16)0.f;
                }
                *(half4_t*)&Bt[r][c0 + j] = hw;
            }
        }
    }
    __syncthreads();
    // ---- out = S2 @ Wc2^T + bc2, 64x10
    f32x4 acc3 = zero;
    #pragma unroll
    for (int kc = 0; kc < 2; ++kc) {
        half4_t af = *(const half4_t*)&At[wave * 16 + lo16][kc * 16 + g * 4];
        half4_t bf = *(const half4_t*)&Bt[lo16][kc * 16 + g * 4];
        acc3 = MFMA16(af, bf, acc3);
    }
    if (lo16 < 10) {
        float bv = bc2[lo16];
        #pragma unroll
        for (int reg = 0; reg < 4; ++reg) {
            int row = brow + wave * 16 + g * 4 + reg;
            outp[(size_t)row * 10 + lo16] = acc3[reg] + bv;
        }
    }
}

// ------------------------------------------------------------------- host side
extern "C" void kernel_launch(void* const* d_in, const int* in_sizes, int n_in,
                              void* d_out, int out_size, void* d_ws, size_t ws_size,
                              hipStream_t stream) {
    const int N = NN, E = EE;
    const float* x    = (const float*)d_in[0];
    const int*   ei   = (const int*)d_in[1];
    const float* W[3]   = {(const float*)d_in[2], (const float*)d_in[6], (const float*)d_in[10]};
    const float* as_[3] = {(const float*)d_in[3], (const float*)d_in[7], (const float*)d_in[11]};
    const float* ad_[3] = {(const float*)d_in[4], (const float*)d_in[8], (const float*)d_in[12]};
    const float* bn_g = (const float*)d_in[14];
    const float* bn_b = (const float*)d_in[15];
    const float* Wq = (const float*)d_in[16];
    const float* Wk = (const float*)d_in[17];
    const float* Wv = (const float*)d_in[18];
    const float* Wo = (const float*)d_in[19];
    const float* bq = (const float*)d_in[20];
    const float* bk = (const float*)d_in[21];
    const float* bv = (const float*)d_in[22];
    const float* bo = (const float*)d_in[23];
    const float* Wc1 = (const float*)d_in[24];
    const float* bc1 = (const float*)d_in[25];
    const float* Wc2 = (const float*)d_in[26];
    const float* bc2 = (const float*)d_in[27];

    char* ws = (char*)d_ws;
    _Float16* h16 = (_Float16*)(ws + 0);       // 8192*512*2 = 8,388,608 (GAT phase)
    _Float16* qh = (_Float16*)(ws + 9437184);  // 1,048,576 (MHA phase)
    _Float16* kh = (_Float16*)(ws + 10485760); // 1,048,576
    _Float16* vh = (_Float16*)(ws + 11534336); // 1,048,576
    _Float16* vt = (_Float16*)(ws + 12582912); // 1,048,576
    _Float16* khp = (_Float16*)(ws + 13631488);// 1,048,576
    float* a_s  = (float*)(ws + 16777216);     // 262,144
    float* a_d  = (float*)(ws + 17039360);     // 262,144
    int* row_ptr = (int*)(ws + 17301504);      // 33,024
    int* cursor  = (int*)(ws + 17334528);      // 32,768
    int* deg     = (int*)(ws + 17367296);      // 32,768
    int* col     = (int*)(ws + 17400064);      // 1,081,344
    float* g0   = (float*)(ws + 18481408);     // 2,097,152
    float* g1   = (float*)(ws + 20578560);     // 2,097,152
    float* ao   = (float*)(ws + 28967168);     // 2,097,152
    float* bnscale = (float*)(ws + 32112896);  // 64
    float* bnshift = bnscale + 64;             // 64

    // ---- CSR build (same graph all layers); self-loops via +1 in scan_deg
    hipMemsetAsync(deg, 0, (size_t)N * 4, stream);
    count_deg<<<(E + 255) / 256, 256, 0, stream>>>(ei, deg, E);
    scan_deg<<<1, 1024, 0, stream>>>(deg, row_ptr, cursor, N);
    fill_csr<<<(E + N + 255) / 256, 256, 0, stream>>>(ei, cursor, col, E, N);

    // ---- 3 GAT layers. gat_coef fused into GEMM epilogue; BN+ReLU of layer i
    // fused into layer i+1's (or qkv's) A-staging. No float atomics anywhere.
    // L0 (H=8, K=128, no BN on input x)
    mfma_gemm<false, true, 0, true, false><<<dim3(8, N / 64), 256, 0, stream>>>(
        x, W[0], nullptr, h16, N, 512, 128, 1.f, as_[0], ad_[0], a_s, a_d, 8, nullptr, nullptr);
    gat_gather_h8<<<N / 4, 256, 0, stream>>>(h16, a_s, a_d, row_ptr, col, g0, N);
    bn_stats<<<64, 256, 0, stream>>>(g0, bn_g, bn_b, bnscale, bnshift, N);
    // L1 (H=8, K=64, BN0 fused)
    mfma_gemm<false, true, 0, true, true><<<dim3(8, N / 64), 256, 0, stream>>>(
        g0, W[1], nullptr, h16, N, 512, 64, 1.f, as_[1], ad_[1], a_s, a_d, 8, bnscale, bnshift);
    gat_gather_h8<<<N / 4, 256, 0, stream>>>(h16, a_s, a_d, row_ptr, col, g1, N);
    bn_stats<<<64, 256, 0, stream>>>(g1, bn_g + 64, bn_b + 64, bnscale, bnshift, N);
    // L2 (H=1, K=64, BN1 fused); gather is plain-store -> g0 reusable
    mfma_gemm<false, true, 0, true, true><<<dim3(1, N / 64), 256, 0, stream>>>(
        g1, W[2], nullptr, h16, N, 64, 64, 1.f, as_[2], ad_[2], a_s, a_d, 1, bnscale, bnshift);
    gat_gather_h1<<<N / 4, 256, 0, stream>>>(h16, a_s, a_d, row_ptr, col, g0, N);
    bn_stats<<<64, 256, 0, stream>>>(g0, bn_g + 128, bn_b + 128, bnscale, bnshift, N);

    // ---- MHA (4 heads, hd=16): QKV proj with BN2 fused; exp2-domain flash
    // Q scale = 0.25 (1/sqrt(hd)) * log2(e) -> softmax in exp2 domain
    qkv_gemm<<<dim3(1, N / 64, 3), 256, 0, stream>>>(
        g0, Wq, Wk, Wv, bq, bk, bv, qh, kh, vh, N, 0.36067376f, bnscale, bnshift);
    vkpack<<<N / 64, 256, 0, stream>>>(vh, kh, vt, khp, N);
    mha_fa5<<<dim3(N / 32, 4), 512, 0, stream>>>(qh, khp, vt, ao, N);

    // ---- fused output head: Wo -> relu(Wc1) -> Wc2
    mlp_head<<<N / 64, 256, 0, stream>>>(ao, Wo, bo, Wc1, bc1, Wc2, bc2, (float*)d_out, N);
}